// Round 1
// baseline (507.603 us; speedup 1.0000x reference)
//
#include <hip/hip_runtime.h>

// Problem constants (fixed by the reference): B=16, M=1024, V=4.
#define M_DIM 1024
#define M_SHIFT 10
#define BLOCK 256
#define GRID 2048
#define UNROLL 8
#define CHUNK (BLOCK * UNROLL)   // 2048 float4 elements = exactly 2 rows (M=1024)

// ws layout: part[GRID] float4 partials (tt, ss, it, is per block) = 32 KiB.

__global__ __launch_bounds__(BLOCK, 4)
void pose_loss_partial(const float4* __restrict__ pred,
                       const float4* __restrict__ gt,
                       const int* __restrict__ Ms, int V,
                       long long N, float4* __restrict__ part)
{
    // cumulative start offsets of each view (V <= 8 supported)
    int cum[9];
    cum[0] = 0;
#pragma unroll
    for (int v = 0; v < 8; ++v) {
        int m = (v < V) ? Ms[v] : 0;
        cum[v + 1] = cum[v] + m;
    }

    const int t = threadIdx.x;

    // Column-band view ids: within a row, this thread always touches
    // j = q*256 + t for q = 0..3 (M_DIM / BLOCK = 4). Compute once.
    int vj[4];
#pragma unroll
    for (int q = 0; q < 4; ++q) {
        int j = q * BLOCK + t;
        int vid = 0;
#pragma unroll
        for (int v = 1; v < 8; ++v)
            if (v < V) vid += (j >= cum[v]);
        vj[q] = vid;
    }

    float tt = 0.f, ss = 0.f, it = 0.f, is = 0.f;

    const long long nchunks = N / CHUNK;
    for (long long c = blockIdx.x; c < nchunks; c += gridDim.x) {
        const long long base = c * CHUNK;

        // chunk covers rows 2c and 2c+1; i = row mod M_DIM. Since chunks are
        // 2-row aligned, i0 is even and i1 = i0+1 never wraps.
        const int i0 = (int)((c * 2) & (M_DIM - 1));
        int vi0 = 0, vi1 = 0;
#pragma unroll
        for (int v = 1; v < 8; ++v) {
            if (v < V) {
                vi0 += (i0 >= cum[v]);
                vi1 += (i0 + 1 >= cum[v]);
            }
        }

        // Inter-view weight per unrolled slot k: k=0..3 -> row i0 band k,
        // k=4..7 -> row i1 band k-4.  (off = k*256 + t, j = off & 1023,
        // row = i0 + (off >> 10)).
        float w[UNROLL];
#pragma unroll
        for (int q = 0; q < 4; ++q) {
            w[q]     = (vj[q] != vi0) ? 1.0f : 0.0f;
            w[q + 4] = (vj[q] != vi1) ? 1.0f : 0.0f;
        }

        // Batched loads: 16 dwordx4 in flight per thread (256 B/lane MLP).
        float4 p[UNROLL], g[UNROLL];
#pragma unroll
        for (int k = 0; k < UNROLL; ++k) {
            const long long off = base + k * BLOCK + t;
            p[k] = pred[off];
            g[k] = gt[off];
        }
#pragma unroll
        for (int k = 0; k < UNROLL; ++k) {
            const float d0 = p[k].x - g[k].x;
            const float d1 = p[k].y - g[k].y;
            const float d2 = p[k].z - g[k].z;
            const float d3 = p[k].w - g[k].w;
            const float tv = d0 * d0 + d1 * d1;
            const float sv = d2 * d2 + d3 * d3;
            tt += tv;
            ss += sv;
            it = fmaf(tv, w[k], it);
            is = fmaf(sv, w[k], is);
        }
    }

    // Generic tail (never taken for the fixed B=16, M=1024 problem).
    for (long long idx = nchunks * CHUNK + (long long)blockIdx.x * BLOCK + t;
         idx < N; idx += (long long)gridDim.x * BLOCK) {
        const int j = (int)(idx & (M_DIM - 1));
        const int i = (int)((idx >> M_SHIFT) & (M_DIM - 1));
        float4 p = pred[idx];
        float4 g = gt[idx];
        float d0 = p.x - g.x, d1 = p.y - g.y, d2 = p.z - g.z, d3 = p.w - g.w;
        float tv = d0 * d0 + d1 * d1;
        float sv = d2 * d2 + d3 * d3;
        int vi = 0, vjj = 0;
#pragma unroll
        for (int v = 1; v < 8; ++v) {
            if (v < V) {
                vi += (i >= cum[v]);
                vjj += (j >= cum[v]);
            }
        }
        float wv = (vi != vjj) ? 1.0f : 0.0f;
        tt += tv;
        ss += sv;
        it = fmaf(tv, wv, it);
        is = fmaf(sv, wv, is);
    }

    // 64-lane wave reduction
#pragma unroll
    for (int off = 32; off > 0; off >>= 1) {
        tt += __shfl_down(tt, off);
        ss += __shfl_down(ss, off);
        it += __shfl_down(it, off);
        is += __shfl_down(is, off);
    }

    __shared__ float l_tt[BLOCK / 64], l_ss[BLOCK / 64],
                     l_it[BLOCK / 64], l_is[BLOCK / 64];
    int wave = threadIdx.x >> 6;
    int lane = threadIdx.x & 63;
    if (lane == 0) {
        l_tt[wave] = tt; l_ss[wave] = ss;
        l_it[wave] = it; l_is[wave] = is;
    }
    __syncthreads();
    if (threadIdx.x == 0) {
        float a = 0.f, b = 0.f, cc = 0.f, d = 0.f;
#pragma unroll
        for (int w2 = 0; w2 < BLOCK / 64; ++w2) {
            a += l_tt[w2]; b += l_ss[w2]; cc += l_it[w2]; d += l_is[w2];
        }
        part[blockIdx.x] = make_float4(a, b, cc, d);  // private slot: no contention
    }
}

__global__ void pose_loss_final(const float4* __restrict__ part, int nparts,
                                const int* __restrict__ Ms, int V, int B,
                                float* __restrict__ out)
{
    // One block of 256 threads; each sums nparts/256 slots, then reduces.
    double tt = 0.0, ss = 0.0, it = 0.0, is = 0.0;
    for (int k = threadIdx.x; k < nparts; k += BLOCK) {
        float4 q = part[k];
        tt += q.x; ss += q.y; it += q.z; is += q.w;
    }
#pragma unroll
    for (int off = 32; off > 0; off >>= 1) {
        tt += __shfl_down(tt, off);
        ss += __shfl_down(ss, off);
        it += __shfl_down(it, off);
        is += __shfl_down(is, off);
    }
    __shared__ double l_tt[BLOCK / 64], l_ss[BLOCK / 64],
                      l_it[BLOCK / 64], l_is[BLOCK / 64];
    int wave = threadIdx.x >> 6;
    int lane = threadIdx.x & 63;
    if (lane == 0) {
        l_tt[wave] = tt; l_ss[wave] = ss;
        l_it[wave] = it; l_is[wave] = is;
    }
    __syncthreads();
    if (threadIdx.x == 0) {
        double s_tt = 0, s_ss = 0, s_it = 0, s_is = 0;
#pragma unroll
        for (int w = 0; w < BLOCK / 64; ++w) {
            s_tt += l_tt[w]; s_ss += l_ss[w];
            s_it += l_it[w]; s_is += l_is[w];
        }
        long long sumsq = 0;
        for (int v = 0; v < V; ++v) {
            long long m = Ms[v];
            sumsq += m * m;
        }
        double diag = (double)sumsq * (double)B;
        double offd = ((double)M_DIM * (double)M_DIM - (double)sumsq) * (double)B;

        double li_t = (s_tt - s_it) / diag;
        double le_t = s_it / offd;
        double li_s = (s_ss - s_is) / diag;
        double le_s = s_is / offd;

        const double A_T = 0.5, A_S = 0.75, A_TS = 0.5;
        double lt = A_T * le_t + (1.0 - A_T) * li_t;
        double ls = A_S * le_s + (1.0 - A_S) * li_s;
        double loss = A_TS * lt + (1.0 - A_TS) * ls;

        out[0] = (float)li_t;
        out[1] = (float)le_t;
        out[2] = (float)li_s;
        out[3] = (float)le_s;
        out[4] = (float)lt;
        out[5] = (float)ls;
        out[6] = (float)loss;
    }
}

extern "C" void kernel_launch(void* const* d_in, const int* in_sizes, int n_in,
                              void* d_out, int out_size, void* d_ws, size_t ws_size,
                              hipStream_t stream)
{
    const float* pred = (const float*)d_in[0];
    const float* gt   = (const float*)d_in[1];
    const int*   Ms   = (const int*)d_in[2];
    int V = in_sizes[2];

    long long total = (long long)in_sizes[0];            // B*M*M*4
    long long N     = total / 4;                         // float4 groups
    int B           = (int)(total / (4LL * M_DIM * M_DIM));

    float4* part = (float4*)d_ws;                        // GRID slots, 32 KiB

    pose_loss_partial<<<GRID, BLOCK, 0, stream>>>(
        (const float4*)pred, (const float4*)gt, Ms, V, N, part);
    pose_loss_final<<<1, BLOCK, 0, stream>>>(part, GRID, Ms, V, B,
                                             (float*)d_out);
}